// Round 7
// baseline (553.054 us; speedup 1.0000x reference)
//
#include <hip/hip_runtime.h>
#include <hip/hip_bf16.h>
#include <stdint.h>

#define N_TOK 8192
#define DMODEL 1024
#define HDIM 4096
#define NEXP 8
#define CAP 2048  // k*N/E
#define GATE_BLOCKS (N_TOK / 4)

typedef float floatx4 __attribute__((ext_vector_type(4)));
typedef int int32x4_t __attribute__((ext_vector_type(4)));
typedef int int32x8_t __attribute__((ext_vector_type(8)));

static __device__ __forceinline__ void async_copy16(const void* g, void* l) {
  __builtin_amdgcn_global_load_lds(
      (const __attribute__((address_space(1))) void*)g,
      (__attribute__((address_space(3))) void*)l, 16, 0, 0);
}

// pack 4 floats -> 4 fp8(e4m3) bytes in one dword
static __device__ __forceinline__ unsigned int pk4_fp8(float a, float b, float c, float d) {
  int r = __builtin_amdgcn_cvt_pk_fp8_f32(a, b, 0, 0);
  r = __builtin_amdgcn_cvt_pk_fp8_f32(c, d, r, 1);
  return (unsigned int)r;
}

static __device__ __forceinline__ unsigned short f2bf(float f) {
  union { float f; uint32_t u; } v; v.f = f;
  uint32_t r = (v.u + 0x7FFFu + ((v.u >> 16) & 1u)) >> 16;
  return (unsigned short)r;
}

static __device__ __forceinline__ float bf2f(unsigned short u) {
  union { float f; uint32_t u32; } v; v.u32 = ((uint32_t)u) << 16;
  return v.f;
}

// ---- fused: weight transpose+cvt (independent) + gate (head of dep chain) --
// grid (64, 4, 24), block 256:
//   z in [0,8):   fc1_w [E][D][H] -> fc1t [E][H][D] fp8*512  (R=DMODEL,C=HDIM)
//   z in [8,16):  fc2_w [E][H][D] -> fc2t [E][D][H] fp8*512  (R=HDIM,C=DMODEL)
//   z in [16,24): gate block gb=(z-16)*256+by*64+bx, 4 tokens/block
// Transpose tile: 256 rows x 64 cols (64 KB LDS, 2 blocks/CU).
// R6 A/B motivation: old 128x32 tile ran at 1.75 TB/s (22% peak) with 128-B
// read/write segments. 256x64 doubles both segment lengths to 256 B and
// quadruples per-thread MLP (16 float4 loads in flight), targeting DRAM
// efficiency. LDS: read-phase 2-way (free); write-phase 8-way but LDS time
// is ~5x under the HBM time per block -> not binding.
__global__ __launch_bounds__(256) void gate_transpose_kernel(
    const float* __restrict__ fc1_w, unsigned char* __restrict__ fc1t,
    const float* __restrict__ fc2_w, unsigned char* __restrict__ fc2t,
    const float* __restrict__ x, const float* __restrict__ wg,
    float* __restrict__ topv, int* __restrict__ topi,
    float* __restrict__ me_part, int* __restrict__ ce_part) {
  __shared__ float tile[64][257];  // [c][r], +1 col pad
  __shared__ float sm_p[4][NEXP];
  __shared__ int sm_i0[4];
  int z = blockIdx.z;
  int t = threadIdx.x;
  if (z < 16) {
    // ---------------- transpose + cvt branch ----------------
    const float* in; unsigned char* out; int R, C, c0, r0, zz;
    if (z < 8) {
      in = fc1_w; out = fc1t; R = DMODEL; C = HDIM; zz = z;
      c0 = blockIdx.x * 64;                 // 64 c-tiles
      r0 = blockIdx.y * 256;                // 4 r-tiles
    } else {
      in = fc2_w; out = fc2t; R = HDIM; C = DMODEL; zz = z - 8;
      c0 = (blockIdx.x & 15) * 64;          // 16 c-tiles
      r0 = ((blockIdx.x >> 4) + blockIdx.y * 4) * 256;  // 16 r-tiles
    }
    const float* inp = in + (size_t)zz * R * C;
    unsigned char* outp = out + (size_t)zz * R * C;
    int tr = t >> 4;          // 0..15
    int tc4 = (t & 15) * 4;   // 0..60
    // read: 16 passes x 16 rows; each row read as 64 floats (256 B) by 16 lanes
#pragma unroll
    for (int p = 0; p < 16; p++) {
      int r = p * 16 + tr;
      float4 v = *(const float4*)(inp + (size_t)(r0 + r) * C + c0 + tc4);
      tile[tc4 + 0][r] = v.x; tile[tc4 + 1][r] = v.y;
      tile[tc4 + 2][r] = v.z; tile[tc4 + 3][r] = v.w;
    }
    __syncthreads();
    // write: 4 passes x 16 out-rows; each out-row gets 256 fp8 B from 16 lanes
    int r16 = (t & 15) * 16;
#pragma unroll
    for (int q = 0; q < 4; q++) {
      int c = q * 16 + tr;
      unsigned int w[4];
#pragma unroll
      for (int j = 0; j < 4; j++) {
        float a = tile[c][r16 + j * 4 + 0] * 512.f;
        float b = tile[c][r16 + j * 4 + 1] * 512.f;
        float cc2 = tile[c][r16 + j * 4 + 2] * 512.f;
        float d = tile[c][r16 + j * 4 + 3] * 512.f;
        w[j] = pk4_fp8(a, b, cc2, d);
      }
      uint4 o; o.x = w[0]; o.y = w[1]; o.z = w[2]; o.w = w[3];
      *(uint4*)(outp + (size_t)(c0 + c) * R + r0 + r16) = o;
    }
    return;
  }
  // ---------------- gate branch ----------------
  int gb = (z - 16) * 256 + blockIdx.y * 64 + blockIdx.x;  // [0, 2048)
  int wave = t >> 6;
  int lane = t & 63;
  int n = gb * 4 + wave;
  float acc[NEXP];
#pragma unroll
  for (int e = 0; e < NEXP; e++) acc[e] = 0.f;
  const float* xr = x + (size_t)n * DMODEL;
#pragma unroll 4
  for (int i = 0; i < DMODEL / 64; i++) {
    int idx = lane + 64 * i;
    float xv = xr[idx];
    const float4* wr = (const float4*)(wg + (size_t)idx * NEXP);
    float4 w0 = wr[0], w1 = wr[1];
    acc[0] += xv * w0.x; acc[1] += xv * w0.y;
    acc[2] += xv * w0.z; acc[3] += xv * w0.w;
    acc[4] += xv * w1.x; acc[5] += xv * w1.y;
    acc[6] += xv * w1.z; acc[7] += xv * w1.w;
  }
#pragma unroll
  for (int e = 0; e < NEXP; e++) {
    float v = acc[e];
#pragma unroll
    for (int off = 32; off > 0; off >>= 1) v += __shfl_down(v, off, 64);
    acc[e] = v;
  }
  if (lane == 0) {
    float mx = acc[0];
#pragma unroll
    for (int e = 1; e < NEXP; e++) mx = fmaxf(mx, acc[e]);
    float p[NEXP]; float s = 0.f;
#pragma unroll
    for (int e = 0; e < NEXP; e++) { p[e] = expf(acc[e] - mx); s += p[e]; }
    float inv = 1.f / s;
#pragma unroll
    for (int e = 0; e < NEXP; e++) p[e] *= inv;
    int i0 = 0; float v0 = p[0];
#pragma unroll
    for (int e = 1; e < NEXP; e++) if (p[e] > v0) { v0 = p[e]; i0 = e; }
    int i1 = -1; float v1 = -1.f;
#pragma unroll
    for (int e = 0; e < NEXP; e++) {
      if (e == i0) continue;
      if (p[e] > v1) { v1 = p[e]; i1 = e; }
    }
    topv[n * 2] = v0; topv[n * 2 + 1] = v1;
    topi[n * 2] = i0; topi[n * 2 + 1] = i1;
#pragma unroll
    for (int e = 0; e < NEXP; e++) sm_p[wave][e] = p[e];
    sm_i0[wave] = i0;
  }
  __syncthreads();
  if (t < NEXP) {
    int e = t;
    float pm = 0.f; int cc = 0;
#pragma unroll
    for (int w = 0; w < 4; w++) {
      pm += sm_p[w][e];
      cc += (sm_i0[w] == e) ? 1 : 0;
    }
    me_part[gb * NEXP + e] = pm;
    ce_part[gb * NEXP + e] = cc;
  }
}

// -------- slot-major positional scan (single block) + fused l_aux -----------
__global__ __launch_bounds__(1024) void scan_kernel(
    const int* __restrict__ topi, const float* __restrict__ topv,
    int* __restrict__ flat_idx, float* __restrict__ cw,
    const float* __restrict__ me_part, const int* __restrict__ ce_part,
    float* __restrict__ out_laux) {
  __shared__ int hist[16][NEXP];
  __shared__ int base[NEXP];
  __shared__ float redm[NEXP][2];
  __shared__ float redc[NEXP][2];
  int tid = threadIdx.x;
  int w = tid >> 6, lane = tid & 63;
  if (tid < NEXP) base[tid] = 0;
  int vals[16];
#pragma unroll
  for (int c = 0; c < 16; c++) {
    int j = c * 1024 + tid;
    vals[c] = topi[(size_t)(j & 8191) * 2 + (j >> 13)];
  }
  __syncthreads();
  for (int c = 0; c < 16; c++) {
    int j = c * 1024 + tid;
    int slot = j >> 13;
    int n = j & 8191;
    int e = vals[c];
    int rank = 0;
#pragma unroll
    for (int ee = 0; ee < NEXP; ee++) {
      unsigned long long m = __ballot(e == ee);
      if (e == ee) rank = __popcll(m & ((1ull << lane) - 1ull));
      if (lane == ee) hist[w][ee] = __popcll(m);
    }
    __syncthreads();
    if (tid < NEXP) {
      int run = base[tid];
#pragma unroll
      for (int ww = 0; ww < 16; ww++) {
        int t = hist[ww][tid];
        hist[ww][tid] = run;
        run += t;
      }
      base[tid] = run;
    }
    __syncthreads();
    int pos = hist[w][e] + rank;
    bool valid = pos < CAP;
    flat_idx[n * 2 + slot] = e * CAP + (valid ? pos : 0);
    cw[n * 2 + slot] = valid ? topv[n * 2 + slot] : 0.f;
    __syncthreads();
  }
  // ---- fused l_aux = E * sum(me * ce) over gate per-block partials ----
  {
    int e2 = tid >> 7, c2 = tid & 127;  // 8 expert groups x 128 threads
    float pm = 0.f, cc = 0.f;
    for (int b = c2; b < GATE_BLOCKS; b += 128) {
      pm += me_part[b * NEXP + e2];
      cc += (float)ce_part[b * NEXP + e2];
    }
#pragma unroll
    for (int off = 32; off > 0; off >>= 1) {
      pm += __shfl_down(pm, off, 64);
      cc += __shfl_down(cc, off, 64);
    }
    if ((tid & 63) == 0) {
      redm[e2][(tid >> 6) & 1] = pm;
      redc[e2][(tid >> 6) & 1] = cc;
    }
    __syncthreads();
    if (tid == 0) {
      float s = 0.f;
#pragma unroll
      for (int ee = 0; ee < NEXP; ee++) {
        float tm2 = redm[ee][0] + redm[ee][1];
        float tc2 = redc[ee][0] + redc[ee][1];
        s += (tm2 / (float)N_TOK) * (tc2 / (float)N_TOK);
      }
      *out_laux = (float)NEXP * s;
    }
  }
}

// ---------------- dispatch scatter: disp[flat] = fp8(x[n]) -------------------
__global__ __launch_bounds__(64) void dispatch_kernel(
    const float* __restrict__ x, const int* __restrict__ flat_idx,
    const float* __restrict__ cw, unsigned char* __restrict__ disp) {
  int a = blockIdx.x;
  if (cw[a] == 0.f) return;
  int n = a >> 1;
  int f = flat_idx[a];
  int lane = threadIdx.x;
  const float4* xr = (const float4*)(x + (size_t)n * DMODEL);
  unsigned int* dr = (unsigned int*)(disp + (size_t)f * DMODEL);
#pragma unroll
  for (int i = 0; i < 4; i++) {
    float4 v = xr[lane + 64 * i];
    dr[lane + 64 * i] = pk4_fp8(v.x, v.y, v.z, v.w);
  }
}

// ------- MX-fp8 MFMA GEMM: C[e] = act(A[e] @ B[e]^T * inv_scale + bias) -----
// A: [E][M][K] fp8 row-major. BT: [E][Ncols][K] fp8. unit MX scales (0x7F).
// grid (Ncols/128, M/128, E), block 256 (4 waves, 2x2 of 64x64 per wave).
// Round-2 measured-best structure INCLUDING the XCD remap (R2-vs-R5 A/B:
// remap = +9% despite FETCH 82->139 MB; kernel is latency-bound, extra
// traffic free, per-XCD expert ownership improves load latency).
// Pipeline: 2-stage-ahead global_load_lds (16/lane in flight), stage-top
// s_waitcnt vmcnt(8) (counted, never drain-0 in main loop), ds_reads in two
// pinned groups, MFMA clusters under counted lgkmcnt(6/4/2/0), stage s+2
// loads issued mid-stage so the stage-top wait stays counted.
// OUT_MODE: 0 = fp32, 1 = fp8 (scaled by out_mult), 2 = bf16
template <int K_DIM, bool RELU, int OUT_MODE>
__global__ __launch_bounds__(256) void gemm_fp8_kernel(
    const unsigned char* __restrict__ A, const unsigned char* __restrict__ BT,
    const float* __restrict__ bias, void* __restrict__ Cout, int M, int Ncols,
    float inv_scale, float out_mult) {
  constexpr int BK = 128;
  constexpr int NSTAGE = K_DIM / BK;
  static_assert(NSTAGE >= 2, "need >=2 K stages for the 2-deep pipeline");
  __shared__ unsigned char As[2][128 * BK];  // 2 x 16KB, xor-swizzled 16B chunks
  __shared__ unsigned char Bs[2][128 * BK];

  // ---- XCD-aware bijective remap (nwg % 8 == 0 for both launches) ----
  unsigned gx = gridDim.x;
  unsigned gxy = gridDim.x * gridDim.y;
  unsigned nwg = gxy * gridDim.z;
  unsigned lid = blockIdx.z * gxy + blockIdx.y * gx + blockIdx.x;
  int e, tm, tn;
  if ((nwg & 7u) == 0u) {
    unsigned chunk = nwg >> 3;
    unsigned w = (lid & 7u) * chunk + (lid >> 3);
    e = w / gxy;
    unsigned rem = w - (unsigned)e * gxy;
    tm = rem / gx;
    tn = rem - (unsigned)tm * gx;
  } else {
    e = blockIdx.z; tm = blockIdx.y; tn = blockIdx.x;
  }

  const unsigned char* Ae = A + (size_t)e * M * K_DIM + (size_t)tm * 128 * K_DIM;
  const unsigned char* Be = BT + (size_t)e * Ncols * K_DIM + (size_t)tn * 128 * K_DIM;
  int wv = threadIdx.x >> 6, l = threadIdx.x & 63;
  int wm = wv >> 1, wn = wv & 1;
  int l15 = l & 15, quad = l >> 4;
  // staging: lane covers LDS chunk (i*256 + wv*64 + l); row r=chunk>>3, slot=l&7
  int rbase = wv * 8 + (l >> 3);
  int cg = (l & 7) ^ ((l >> 3) & 7);  // xor swizzle: slot s of row r holds chunk s^(r&7)
  floatx4 acc[4][4] = {};

#define STAGE_LOADS(k0, buf)                                                   \
  {                                                                            \
    _Pragma("unroll") for (int i = 0; i < 4; i++) {                            \
      int r = rbase + i * 32;                                                  \
      async_copy16(Ae + (size_t)r * K_DIM + (k0) + cg * 16,                    \
                   &As[buf][i * 4096 + wv * 1024]);                            \
      async_copy16(Be + (size_t)r * K_DIM + (k0) + cg * 16,                    \
                   &Bs[buf][i * 4096 + wv * 1024]);                            \
    }                                                                          \
  }

#define READ_AF(mi)                                                            \
  {                                                                            \
    int m = wm * 64 + (mi) * 16 + l15;                                         \
    int x0 = (quad * 2) ^ (m & 7), x1 = (quad * 2 + 1) ^ (m & 7);              \
    int32x4_t lo = *(const int32x4_t*)(&As[cur][m * 128 + x0 * 16]);           \
    int32x4_t hi = *(const int32x4_t*)(&As[cur][m * 128 + x1 * 16]);           \
    af[mi] = __builtin_shufflevector(lo, hi, 0, 1, 2, 3, 4, 5, 6, 7);          \
  }

  STAGE_LOADS(0, 0);
  STAGE_LOADS(BK, 1);  // 16 loads/lane in flight
#pragma unroll
  for (int s = 0; s < NSTAGE; s++) {
    const int cur = s & 1;
    // wait for stage-s tile only; stage s+1's 8 loads stay in flight
    if (s + 1 < NSTAGE)
      asm volatile("s_waitcnt vmcnt(8)" ::: "memory");
    else
      asm volatile("s_waitcnt vmcnt(0)" ::: "memory");
    __builtin_amdgcn_s_barrier();
    int32x8_t af[4], bf[4];
    // --- issue group 1: all B fragments + A fragment 0 (10 x ds_read_b128)
#pragma unroll
    for (int ni = 0; ni < 4; ni++) {
      int m = wn * 64 + ni * 16 + l15;
      int x0 = (quad * 2) ^ (m & 7), x1 = (quad * 2 + 1) ^ (m & 7);
      int32x4_t lo = *(const int32x4_t*)(&Bs[cur][m * 128 + x0 * 16]);
      int32x4_t hi = *(const int32x4_t*)(&Bs[cur][m * 128 + x1 * 16]);
      bf[ni] = __builtin_shufflevector(lo, hi, 0, 1, 2, 3, 4, 5, 6, 7);
    }
    READ_AF(0);
    __builtin_amdgcn_sched_barrier(0);
    // --- issue group 2: A fragments 1..3 (6 x ds_read_b128)
    READ_AF(1);
    READ_AF(2);
    READ_AF(3);
    __builtin_amdgcn_sched_barrier(0);
    __builtin_amdgcn_s_setprio(1);
    // --- cluster 0: needs group 1 (10 oldest done -> 6 outstanding)
    asm volatile("s_waitcnt lgkmcnt(6)" ::: "memory");
    __builtin_amdgcn_sched_barrier(0);
#pragma unroll
    for (int ni = 0; ni < 4; ni++)
      acc[0][ni] = __builtin_amdgcn_mfma_scale_f32_16x16x128_f8f6f4(
          af[0], bf[ni], acc[0][ni], 0, 0, 0, 0x7F7F7F7F, 0, 0x7F7F7F7F);
    asm volatile("s_waitcnt lgkmcnt(4)" ::: "memory");
    __builtin_amdgcn_sched_barrier(0);
#pragma unroll
    for (int ni = 0; ni < 4; ni++)
      acc[1][ni] = __builtin_amdgcn_mfma_scale_f32_16x16x128_f8f6f4(
          af[1], bf[ni], acc[1][ni], 0, 0, 0, 0x7F7F7F7F, 0, 0x7F7F7F7F);
    asm volatile("s_waitcnt lgkmcnt(2)" ::: "memory");
    __builtin_amdgcn_sched_barrier(0);
#pragma unroll
    for (int ni = 0; ni < 4; ni++)
      acc[2][ni] = __builtin_amdgcn_mfma_scale_f32_16x16x128_f8f6f4(
          af[2], bf[ni], acc[2][ni], 0, 0, 0, 0x7F7F7F7F, 0, 0x7F7F7F7F);
    asm volatile("s_waitcnt lgkmcnt(0)" ::: "memory");
    __builtin_amdgcn_sched_barrier(0);
    __builtin_amdgcn_s_setprio(0);
    // all waves finished reading buf[cur] -> safe to overwrite
    __builtin_amdgcn_s_barrier();
    if (s + 2 < NSTAGE) STAGE_LOADS((s + 2) * BK, cur);  // overlaps cluster 3
    __builtin_amdgcn_s_setprio(1);
#pragma unroll
    for (int ni = 0; ni < 4; ni++)
      acc[3][ni] = __builtin_amdgcn_mfma_scale_f32_16x16x128_f8f6f4(
          af[3], bf[ni], acc[3][ni], 0, 0, 0, 0x7F7F7F7F, 0, 0x7F7F7F7F);
    __builtin_amdgcn_s_setprio(0);
  }
#undef STAGE_LOADS
#undef READ_AF

  // epilogue: C/D layout col = lane&15, row = quad*4 + reg
  int row_base = tm * 128 + wm * 64;
  int col_base = tn * 128 + wn * 64;
  const float* be = bias + (size_t)e * Ncols;
#pragma unroll
  for (int ni = 0; ni < 4; ni++) {
    int col = col_base + ni * 16 + l15;
    float bv = be[col];
#pragma unroll
    for (int mi = 0; mi < 4; mi++) {
#pragma unroll
      for (int r = 0; r < 4; r++) {
        int row = row_base + mi * 16 + quad * 4 + r;
        float v = acc[mi][ni][r] * inv_scale + bv;
        if (RELU) v = fmaxf(v, 0.f);
        size_t idx = (size_t)e * M * Ncols + (size_t)row * Ncols + col;
        if (OUT_MODE == 1) {
          float s = fminf(fmaxf(v * out_mult, -440.f), 440.f);
          unsigned int b8 = (unsigned int)__builtin_amdgcn_cvt_pk_fp8_f32(s, s, 0, 0) & 0xFF;
          ((unsigned char*)Cout)[idx] = (unsigned char)b8;
        } else if (OUT_MODE == 2) {
          ((unsigned short*)Cout)[idx] = f2bf(v);
        } else {
          ((float*)Cout)[idx] = v;
        }
      }
    }
  }
}

// ------- combine: out[n] = sum_s cw[n,s] * y[flat[n,s]], y in bf16 ----------
__global__ __launch_bounds__(256) void combine_kernel(
    const unsigned short* __restrict__ y, const int* __restrict__ flat_idx,
    const float* __restrict__ cw, float* __restrict__ out) {
  int n = blockIdx.x;
  float w0 = cw[n * 2], w1 = cw[n * 2 + 1];
  int f0 = flat_idx[n * 2], f1 = flat_idx[n * 2 + 1];
  const ushort2* y0 = (const ushort2*)(y + (size_t)f0 * DMODEL);
  const ushort2* y1 = (const ushort2*)(y + (size_t)f1 * DMODEL);
  float2* o = (float2*)(out + (size_t)n * DMODEL);
  int t = threadIdx.x;  // 256 threads x 2 elems x 2 iters = 1024
#pragma unroll
  for (int i = 0; i < 2; i++) {
    int j = t + i * 256;
    ushort2 a = y0[j], b = y1[j];
    float2 r;
    r.x = w0 * bf2f(a.x) + w1 * bf2f(b.x);
    r.y = w0 * bf2f(a.y) + w1 * bf2f(b.y);
    o[j] = r;
  }
}

extern "C" void kernel_launch(void* const* d_in, const int* in_sizes, int n_in,
                              void* d_out, int out_size, void* d_ws,
                              size_t ws_size, hipStream_t stream) {
  (void)in_sizes; (void)n_in; (void)out_size; (void)ws_size;
  const float* x     = (const float*)d_in[0];
  const float* wg    = (const float*)d_in[1];
  const float* fc1_w = (const float*)d_in[2];
  const float* fc1_b = (const float*)d_in[3];
  const float* fc2_w = (const float*)d_in[4];
  const float* fc2_b = (const float*)d_in[5];
  float* out = (float*)d_out;

  char* ws = (char*)d_ws;
  size_t o = 0;
  unsigned char* fc1t = (unsigned char*)(ws + o); o += (size_t)NEXP * DMODEL * HDIM;  // 32MB
  unsigned char* fc2t = (unsigned char*)(ws + o); o += (size_t)NEXP * DMODEL * HDIM;  // 32MB
  unsigned char* disp = (unsigned char*)(ws + o); o += (size_t)NEXP * CAP * DMODEL;   // 16MB
  unsigned char* hbuf = (unsigned char*)(ws + o); o += (size_t)NEXP * CAP * HDIM;     // 64MB
  unsigned short* ybuf = (unsigned short*)(ws + o); o += (size_t)NEXP * CAP * DMODEL * 2;  // 32MB bf16
  float* topv = (float*)(ws + o); o += (size_t)N_TOK * 2 * 4;
  int* topi   = (int*)(ws + o);   o += (size_t)N_TOK * 2 * 4;
  int* flat   = (int*)(ws + o);   o += (size_t)N_TOK * 2 * 4;
  float* cw   = (float*)(ws + o); o += (size_t)N_TOK * 2 * 4;
  float* mep  = (float*)(ws + o); o += (size_t)GATE_BLOCKS * NEXP * 4;
  int* cep    = (int*)(ws + o);   o += (size_t)GATE_BLOCKS * NEXP * 4;

  // no memset of disp: unwritten capacity rows are never gathered (cw==0),
  // and fp8-e4m3 bit patterns are always finite.

  // fused: both weight transposes (independent) + gate (dep-chain head)
  gate_transpose_kernel<<<dim3(64, 4, 24), 256, 0, stream>>>(
      fc1_w, fc1t, fc2_w, fc2t, x, wg, topv, topi, mep, cep);
  // scan also computes l_aux (fused)
  scan_kernel<<<1, 1024, 0, stream>>>(topi, topv, flat, cw, mep, cep,
                                      out + (size_t)N_TOK * DMODEL);
  dispatch_kernel<<<N_TOK * 2, 64, 0, stream>>>(x, flat, cw, disp);
  // h = relu(disp@fc1^T /512 + b1); stored as fp8 of h*16
  gemm_fp8_kernel<DMODEL, true, 1>
      <<<dim3(HDIM / 128, CAP / 128, NEXP), 256, 0, stream>>>(
          disp, fc1t, fc1_b, hbuf, CAP, HDIM, 1.f / 512.f, 16.f);
  // y = (h*16)@(fc2*512)^T /8192 + b2 ; bf16
  gemm_fp8_kernel<HDIM, false, 2>
      <<<dim3(DMODEL / 128, CAP / 128, NEXP), 256, 0, stream>>>(
          hbuf, fc2t, fc2_b, ybuf, CAP, DMODEL, 1.f / 8192.f, 1.f);
  combine_kernel<<<N_TOK, 256, 0, stream>>>(ybuf, flat, cw, out);
}

// Round 8
// 544.416 us; speedup vs baseline: 1.0159x; 1.0159x over previous
//
#include <hip/hip_runtime.h>
#include <hip/hip_bf16.h>
#include <stdint.h>

#define N_TOK 8192
#define DMODEL 1024
#define HDIM 4096
#define NEXP 8
#define CAP 2048  // k*N/E
#define GATE_BLOCKS (N_TOK / 4)

typedef float floatx4 __attribute__((ext_vector_type(4)));
typedef int int32x4_t __attribute__((ext_vector_type(4)));
typedef int int32x8_t __attribute__((ext_vector_type(8)));

static __device__ __forceinline__ void async_copy16(const void* g, void* l) {
  __builtin_amdgcn_global_load_lds(
      (const __attribute__((address_space(1))) void*)g,
      (__attribute__((address_space(3))) void*)l, 16, 0, 0);
}

// pack 4 floats -> 4 fp8(e4m3) bytes in one dword
static __device__ __forceinline__ unsigned int pk4_fp8(float a, float b, float c, float d) {
  int r = __builtin_amdgcn_cvt_pk_fp8_f32(a, b, 0, 0);
  r = __builtin_amdgcn_cvt_pk_fp8_f32(c, d, r, 1);
  return (unsigned int)r;
}

static __device__ __forceinline__ unsigned short f2bf(float f) {
  union { float f; uint32_t u; } v; v.f = f;
  uint32_t r = (v.u + 0x7FFFu + ((v.u >> 16) & 1u)) >> 16;
  return (unsigned short)r;
}

static __device__ __forceinline__ float bf2f(unsigned short u) {
  union { float f; uint32_t u32; } v; v.u32 = ((uint32_t)u) << 16;
  return v.f;
}

// ---- fused: weight transpose+cvt (independent) + gate (head of dep chain) --
// grid (64, 48), block 256:
//   y in [0,8):   fc1_w [E][D][H] -> fc1t [E][H][D] fp8*512  (R=DMODEL,C=HDIM)
//   y in [8,16):  fc2_w [E][H][D] -> fc2t [E][D][H] fp8*512  (R=HDIM,C=DMODEL)
//   y in [16,48): gate block gb=(y-16)*64+x, 4 tokens/block
//
// Transpose: 256x256 tile, fp8-in-LDS (64 KB + pad).
// R6/R7 A/B showed 128-B vs 256-B read segments both stream at 1.7 TB/s
// (~27% of peak) regardless of occupancy/MLP -> DRAM row-buffer efficiency
// hypothesis: sub-KB segments at power-of-2 stride use ~25% of each DRAM
// row activation. This version reads 1-KB contiguous runs (wave = 64 lanes
// x float4 = one full 256-float row per instruction), converts fp32->fp8 in
// registers, transposes 4x4 bytes via v_perm_b32 (8 perms / 16 floats),
// stages column-major dwords in LDS, writes 256-B coalesced segments.
// Write side stays 256-B but is only 64 MB (vs 256 MB read).
// LDS: write phase 8-way bank conflict (stride 4*65 dwords == 4 mod 32),
// ~1.5 K cyc/wave total -- masked by ~64 K cyc of HBM per block pair.
__global__ __launch_bounds__(256) void gate_transpose_kernel(
    const float* __restrict__ fc1_w, unsigned char* __restrict__ fc1t,
    const float* __restrict__ fc2_w, unsigned char* __restrict__ fc2t,
    const float* __restrict__ x, const float* __restrict__ wg,
    float* __restrict__ topv, int* __restrict__ topi,
    float* __restrict__ me_part, int* __restrict__ ce_part) {
  __shared__ unsigned int ldsT[256 * 65];  // [c][r/4 dwords], +1 dword pad
  __shared__ float sm_p[4][NEXP];
  __shared__ int sm_i0[4];
  int y = blockIdx.y;
  int t = threadIdx.x;
  int w = t >> 6, l = t & 63;
  if (y < 16) {
    // ---------------- transpose + cvt branch ----------------
    const float* in; unsigned char* out; int R, C, r0, c0, zz;
    int tt = blockIdx.x;
    if (y < 8) {
      in = fc1_w; out = fc1t; R = DMODEL; C = HDIM; zz = y;
      r0 = (tt & 3) * 256;         // 4 r-tiles
      c0 = (tt >> 2) * 256;        // 16 c-tiles
    } else {
      in = fc2_w; out = fc2t; R = HDIM; C = DMODEL; zz = y - 8;
      r0 = (tt >> 2) * 256;        // 16 r-tiles
      c0 = (tt & 3) * 256;         // 4 c-tiles
    }
    const float* inp = in + (size_t)zz * R * C + c0;
    unsigned char* outp = out + (size_t)zz * R * C + r0;
    // stage: wave w handles rows [64w, 64w+64); per instruction the wave
    // reads ONE full 256-float row (1 KB contiguous). Lane l covers cols
    // 4l..4l+3. 4-row groups are transposed 4x4 in registers.
#pragma unroll 4
    for (int g = 0; g < 16; g++) {
      int rr = 64 * w + 4 * g;
      float4 v0 = *(const float4*)(inp + (size_t)(r0 + rr + 0) * C + 4 * l);
      float4 v1 = *(const float4*)(inp + (size_t)(r0 + rr + 1) * C + 4 * l);
      float4 v2 = *(const float4*)(inp + (size_t)(r0 + rr + 2) * C + 4 * l);
      float4 v3 = *(const float4*)(inp + (size_t)(r0 + rr + 3) * C + 4 * l);
      unsigned D0 = pk4_fp8(v0.x * 512.f, v0.y * 512.f, v0.z * 512.f, v0.w * 512.f);
      unsigned D1 = pk4_fp8(v1.x * 512.f, v1.y * 512.f, v1.z * 512.f, v1.w * 512.f);
      unsigned D2 = pk4_fp8(v2.x * 512.f, v2.y * 512.f, v2.z * 512.f, v2.w * 512.f);
      unsigned D3 = pk4_fp8(v3.x * 512.f, v3.y * 512.f, v3.z * 512.f, v3.w * 512.f);
      // 4x4 byte transpose: T_k = [D0.k, D1.k, D2.k, D3.k]
      // perm(a,b,sel): sel 0-3 -> b bytes, 4-7 -> a bytes
      unsigned E0 = __builtin_amdgcn_perm(D1, D0, 0x05010400u);  // [D0.0,D1.0,D0.1,D1.1]
      unsigned E1 = __builtin_amdgcn_perm(D1, D0, 0x07030602u);  // [D0.2,D1.2,D0.3,D1.3]
      unsigned F0 = __builtin_amdgcn_perm(D3, D2, 0x05010400u);
      unsigned F1 = __builtin_amdgcn_perm(D3, D2, 0x07030602u);
      unsigned T0 = __builtin_amdgcn_perm(F0, E0, 0x05040100u);  // [D0.0,D1.0,D2.0,D3.0]
      unsigned T1 = __builtin_amdgcn_perm(F0, E0, 0x07060302u);
      unsigned T2 = __builtin_amdgcn_perm(F1, E1, 0x05040100u);
      unsigned T3 = __builtin_amdgcn_perm(F1, E1, 0x07060302u);
      int q = 16 * w + g;  // r-dword index
      ldsT[(4 * l + 0) * 65 + q] = T0;
      ldsT[(4 * l + 1) * 65 + q] = T1;
      ldsT[(4 * l + 2) * 65 + q] = T2;
      ldsT[(4 * l + 3) * 65 + q] = T3;
    }
    __syncthreads();
    // write-out: wave w handles out-rows c in [64w, 64w+64); per instruction
    // 4 out-rows x 16 lanes x 16 B = 4 x 256-B contiguous segments.
    int tr = l >> 4, tq = l & 15;
#pragma unroll 4
    for (int it = 0; it < 16; it++) {
      int c = 64 * w + 4 * it + tr;
      int base = c * 65 + 4 * tq;
      uint4 o;
      o.x = ldsT[base + 0]; o.y = ldsT[base + 1];
      o.z = ldsT[base + 2]; o.w = ldsT[base + 3];
      *(uint4*)(outp + (size_t)(c0 + c) * R + 16 * tq) = o;
    }
    return;
  }
  // ---------------- gate branch ----------------
  int gb = (y - 16) * 64 + blockIdx.x;  // [0, 2048)
  int wave = w;
  int lane = l;
  int n = gb * 4 + wave;
  float acc[NEXP];
#pragma unroll
  for (int e = 0; e < NEXP; e++) acc[e] = 0.f;
  const float* xr = x + (size_t)n * DMODEL;
#pragma unroll 4
  for (int i = 0; i < DMODEL / 64; i++) {
    int idx = lane + 64 * i;
    float xv = xr[idx];
    const float4* wr = (const float4*)(wg + (size_t)idx * NEXP);
    float4 w0 = wr[0], w1 = wr[1];
    acc[0] += xv * w0.x; acc[1] += xv * w0.y;
    acc[2] += xv * w0.z; acc[3] += xv * w0.w;
    acc[4] += xv * w1.x; acc[5] += xv * w1.y;
    acc[6] += xv * w1.z; acc[7] += xv * w1.w;
  }
#pragma unroll
  for (int e = 0; e < NEXP; e++) {
    float v = acc[e];
#pragma unroll
    for (int off = 32; off > 0; off >>= 1) v += __shfl_down(v, off, 64);
    acc[e] = v;
  }
  if (lane == 0) {
    float mx = acc[0];
#pragma unroll
    for (int e = 1; e < NEXP; e++) mx = fmaxf(mx, acc[e]);
    float p[NEXP]; float s = 0.f;
#pragma unroll
    for (int e = 0; e < NEXP; e++) { p[e] = expf(acc[e] - mx); s += p[e]; }
    float inv = 1.f / s;
#pragma unroll
    for (int e = 0; e < NEXP; e++) p[e] *= inv;
    int i0 = 0; float v0 = p[0];
#pragma unroll
    for (int e = 1; e < NEXP; e++) if (p[e] > v0) { v0 = p[e]; i0 = e; }
    int i1 = -1; float v1 = -1.f;
#pragma unroll
    for (int e = 0; e < NEXP; e++) {
      if (e == i0) continue;
      if (p[e] > v1) { v1 = p[e]; i1 = e; }
    }
    topv[n * 2] = v0; topv[n * 2 + 1] = v1;
    topi[n * 2] = i0; topi[n * 2 + 1] = i1;
#pragma unroll
    for (int e = 0; e < NEXP; e++) sm_p[wave][e] = p[e];
    sm_i0[wave] = i0;
  }
  __syncthreads();
  if (t < NEXP) {
    int e = t;
    float pm = 0.f; int cc = 0;
#pragma unroll
    for (int ww = 0; ww < 4; ww++) {
      pm += sm_p[ww][e];
      cc += (sm_i0[ww] == e) ? 1 : 0;
    }
    me_part[gb * NEXP + e] = pm;
    ce_part[gb * NEXP + e] = cc;
  }
}

// -------- slot-major positional scan (single block) + fused l_aux -----------
__global__ __launch_bounds__(1024) void scan_kernel(
    const int* __restrict__ topi, const float* __restrict__ topv,
    int* __restrict__ flat_idx, float* __restrict__ cw,
    const float* __restrict__ me_part, const int* __restrict__ ce_part,
    float* __restrict__ out_laux) {
  __shared__ int hist[16][NEXP];
  __shared__ int base[NEXP];
  __shared__ float redm[NEXP][2];
  __shared__ float redc[NEXP][2];
  int tid = threadIdx.x;
  int w = tid >> 6, lane = tid & 63;
  if (tid < NEXP) base[tid] = 0;
  int vals[16];
#pragma unroll
  for (int c = 0; c < 16; c++) {
    int j = c * 1024 + tid;
    vals[c] = topi[(size_t)(j & 8191) * 2 + (j >> 13)];
  }
  __syncthreads();
  for (int c = 0; c < 16; c++) {
    int j = c * 1024 + tid;
    int slot = j >> 13;
    int n = j & 8191;
    int e = vals[c];
    int rank = 0;
#pragma unroll
    for (int ee = 0; ee < NEXP; ee++) {
      unsigned long long m = __ballot(e == ee);
      if (e == ee) rank = __popcll(m & ((1ull << lane) - 1ull));
      if (lane == ee) hist[w][ee] = __popcll(m);
    }
    __syncthreads();
    if (tid < NEXP) {
      int run = base[tid];
#pragma unroll
      for (int ww = 0; ww < 16; ww++) {
        int t = hist[ww][tid];
        hist[ww][tid] = run;
        run += t;
      }
      base[tid] = run;
    }
    __syncthreads();
    int pos = hist[w][e] + rank;
    bool valid = pos < CAP;
    flat_idx[n * 2 + slot] = e * CAP + (valid ? pos : 0);
    cw[n * 2 + slot] = valid ? topv[n * 2 + slot] : 0.f;
    __syncthreads();
  }
  // ---- fused l_aux = E * sum(me * ce) over gate per-block partials ----
  {
    int e2 = tid >> 7, c2 = tid & 127;  // 8 expert groups x 128 threads
    float pm = 0.f, cc = 0.f;
    for (int b = c2; b < GATE_BLOCKS; b += 128) {
      pm += me_part[b * NEXP + e2];
      cc += (float)ce_part[b * NEXP + e2];
    }
#pragma unroll
    for (int off = 32; off > 0; off >>= 1) {
      pm += __shfl_down(pm, off, 64);
      cc += __shfl_down(cc, off, 64);
    }
    if ((tid & 63) == 0) {
      redm[e2][(tid >> 6) & 1] = pm;
      redc[e2][(tid >> 6) & 1] = cc;
    }
    __syncthreads();
    if (tid == 0) {
      float s = 0.f;
#pragma unroll
      for (int ee = 0; ee < NEXP; ee++) {
        float tm2 = redm[ee][0] + redm[ee][1];
        float tc2 = redc[ee][0] + redc[ee][1];
        s += (tm2 / (float)N_TOK) * (tc2 / (float)N_TOK);
      }
      *out_laux = (float)NEXP * s;
    }
  }
}

// ---------------- dispatch scatter: disp[flat] = fp8(x[n]) -------------------
__global__ __launch_bounds__(64) void dispatch_kernel(
    const float* __restrict__ x, const int* __restrict__ flat_idx,
    const float* __restrict__ cw, unsigned char* __restrict__ disp) {
  int a = blockIdx.x;
  if (cw[a] == 0.f) return;
  int n = a >> 1;
  int f = flat_idx[a];
  int lane = threadIdx.x;
  const float4* xr = (const float4*)(x + (size_t)n * DMODEL);
  unsigned int* dr = (unsigned int*)(disp + (size_t)f * DMODEL);
#pragma unroll
  for (int i = 0; i < 4; i++) {
    float4 v = xr[lane + 64 * i];
    dr[lane + 64 * i] = pk4_fp8(v.x, v.y, v.z, v.w);
  }
}

// ------- MX-fp8 MFMA GEMM: C[e] = act(A[e] @ B[e]^T * inv_scale + bias) -----
// A: [E][M][K] fp8 row-major. BT: [E][Ncols][K] fp8. unit MX scales (0x7F).
// grid (Ncols/128, M/128, E), block 256 (4 waves, 2x2 of 64x64 per wave).
// Round-2 measured-best structure INCLUDING the XCD remap (R2-vs-R5 A/B:
// remap = +9% despite FETCH 82->139 MB; kernel is latency-bound, extra
// traffic free, per-XCD expert ownership improves load latency).
// Pipeline: 2-stage-ahead global_load_lds (16/lane in flight), stage-top
// s_waitcnt vmcnt(8) (counted, never drain-0 in main loop), ds_reads in two
// pinned groups, MFMA clusters under counted lgkmcnt(6/4/2/0), stage s+2
// loads issued mid-stage so the stage-top wait stays counted.
// OUT_MODE: 0 = fp32, 1 = fp8 (scaled by out_mult), 2 = bf16
template <int K_DIM, bool RELU, int OUT_MODE>
__global__ __launch_bounds__(256) void gemm_fp8_kernel(
    const unsigned char* __restrict__ A, const unsigned char* __restrict__ BT,
    const float* __restrict__ bias, void* __restrict__ Cout, int M, int Ncols,
    float inv_scale, float out_mult) {
  constexpr int BK = 128;
  constexpr int NSTAGE = K_DIM / BK;
  static_assert(NSTAGE >= 2, "need >=2 K stages for the 2-deep pipeline");
  __shared__ unsigned char As[2][128 * BK];  // 2 x 16KB, xor-swizzled 16B chunks
  __shared__ unsigned char Bs[2][128 * BK];

  // ---- XCD-aware bijective remap (nwg % 8 == 0 for both launches) ----
  unsigned gx = gridDim.x;
  unsigned gxy = gridDim.x * gridDim.y;
  unsigned nwg = gxy * gridDim.z;
  unsigned lid = blockIdx.z * gxy + blockIdx.y * gx + blockIdx.x;
  int e, tm, tn;
  if ((nwg & 7u) == 0u) {
    unsigned chunk = nwg >> 3;
    unsigned w = (lid & 7u) * chunk + (lid >> 3);
    e = w / gxy;
    unsigned rem = w - (unsigned)e * gxy;
    tm = rem / gx;
    tn = rem - (unsigned)tm * gx;
  } else {
    e = blockIdx.z; tm = blockIdx.y; tn = blockIdx.x;
  }

  const unsigned char* Ae = A + (size_t)e * M * K_DIM + (size_t)tm * 128 * K_DIM;
  const unsigned char* Be = BT + (size_t)e * Ncols * K_DIM + (size_t)tn * 128 * K_DIM;
  int wv = threadIdx.x >> 6, l = threadIdx.x & 63;
  int wm = wv >> 1, wn = wv & 1;
  int l15 = l & 15, quad = l >> 4;
  // staging: lane covers LDS chunk (i*256 + wv*64 + l); row r=chunk>>3, slot=l&7
  int rbase = wv * 8 + (l >> 3);
  int cg = (l & 7) ^ ((l >> 3) & 7);  // xor swizzle: slot s of row r holds chunk s^(r&7)
  floatx4 acc[4][4] = {};

#define STAGE_LOADS(k0, buf)                                                   \
  {                                                                            \
    _Pragma("unroll") for (int i = 0; i < 4; i++) {                            \
      int r = rbase + i * 32;                                                  \
      async_copy16(Ae + (size_t)r * K_DIM + (k0) + cg * 16,                    \
                   &As[buf][i * 4096 + wv * 1024]);                            \
      async_copy16(Be + (size_t)r * K_DIM + (k0) + cg * 16,                    \
                   &Bs[buf][i * 4096 + wv * 1024]);                            \
    }                                                                          \
  }

#define READ_AF(mi)                                                            \
  {                                                                            \
    int m = wm * 64 + (mi) * 16 + l15;                                         \
    int x0 = (quad * 2) ^ (m & 7), x1 = (quad * 2 + 1) ^ (m & 7);              \
    int32x4_t lo = *(const int32x4_t*)(&As[cur][m * 128 + x0 * 16]);           \
    int32x4_t hi = *(const int32x4_t*)(&As[cur][m * 128 + x1 * 16]);           \
    af[mi] = __builtin_shufflevector(lo, hi, 0, 1, 2, 3, 4, 5, 6, 7);          \
  }

  STAGE_LOADS(0, 0);
  STAGE_LOADS(BK, 1);  // 16 loads/lane in flight
#pragma unroll
  for (int s = 0; s < NSTAGE; s++) {
    const int cur = s & 1;
    // wait for stage-s tile only; stage s+1's 8 loads stay in flight
    if (s + 1 < NSTAGE)
      asm volatile("s_waitcnt vmcnt(8)" ::: "memory");
    else
      asm volatile("s_waitcnt vmcnt(0)" ::: "memory");
    __builtin_amdgcn_s_barrier();
    int32x8_t af[4], bf[4];
    // --- issue group 1: all B fragments + A fragment 0 (10 x ds_read_b128)
#pragma unroll
    for (int ni = 0; ni < 4; ni++) {
      int m = wn * 64 + ni * 16 + l15;
      int x0 = (quad * 2) ^ (m & 7), x1 = (quad * 2 + 1) ^ (m & 7);
      int32x4_t lo = *(const int32x4_t*)(&Bs[cur][m * 128 + x0 * 16]);
      int32x4_t hi = *(const int32x4_t*)(&Bs[cur][m * 128 + x1 * 16]);
      bf[ni] = __builtin_shufflevector(lo, hi, 0, 1, 2, 3, 4, 5, 6, 7);
    }
    READ_AF(0);
    __builtin_amdgcn_sched_barrier(0);
    // --- issue group 2: A fragments 1..3 (6 x ds_read_b128)
    READ_AF(1);
    READ_AF(2);
    READ_AF(3);
    __builtin_amdgcn_sched_barrier(0);
    __builtin_amdgcn_s_setprio(1);
    // --- cluster 0: needs group 1 (10 oldest done -> 6 outstanding)
    asm volatile("s_waitcnt lgkmcnt(6)" ::: "memory");
    __builtin_amdgcn_sched_barrier(0);
#pragma unroll
    for (int ni = 0; ni < 4; ni++)
      acc[0][ni] = __builtin_amdgcn_mfma_scale_f32_16x16x128_f8f6f4(
          af[0], bf[ni], acc[0][ni], 0, 0, 0, 0x7F7F7F7F, 0, 0x7F7F7F7F);
    asm volatile("s_waitcnt lgkmcnt(4)" ::: "memory");
    __builtin_amdgcn_sched_barrier(0);
#pragma unroll
    for (int ni = 0; ni < 4; ni++)
      acc[1][ni] = __builtin_amdgcn_mfma_scale_f32_16x16x128_f8f6f4(
          af[1], bf[ni], acc[1][ni], 0, 0, 0, 0x7F7F7F7F, 0, 0x7F7F7F7F);
    asm volatile("s_waitcnt lgkmcnt(2)" ::: "memory");
    __builtin_amdgcn_sched_barrier(0);
#pragma unroll
    for (int ni = 0; ni < 4; ni++)
      acc[2][ni] = __builtin_amdgcn_mfma_scale_f32_16x16x128_f8f6f4(
          af[2], bf[ni], acc[2][ni], 0, 0, 0, 0x7F7F7F7F, 0, 0x7F7F7F7F);
    asm volatile("s_waitcnt lgkmcnt(0)" ::: "memory");
    __builtin_amdgcn_sched_barrier(0);
    __builtin_amdgcn_s_setprio(0);
    // all waves finished reading buf[cur] -> safe to overwrite
    __builtin_amdgcn_s_barrier();
    if (s + 2 < NSTAGE) STAGE_LOADS((s + 2) * BK, cur);  // overlaps cluster 3
    __builtin_amdgcn_s_setprio(1);
#pragma unroll
    for (int ni = 0; ni < 4; ni++)
      acc[3][ni] = __builtin_amdgcn_mfma_scale_f32_16x16x128_f8f6f4(
          af[3], bf[ni], acc[3][ni], 0, 0, 0, 0x7F7F7F7F, 0, 0x7F7F7F7F);
    __builtin_amdgcn_s_setprio(0);
  }
#undef STAGE_LOADS
#undef READ_AF

  // epilogue: C/D layout col = lane&15, row = quad*4 + reg
  int row_base = tm * 128 + wm * 64;
  int col_base = tn * 128 + wn * 64;
  const float* be = bias + (size_t)e * Ncols;
#pragma unroll
  for (int ni = 0; ni < 4; ni++) {
    int col = col_base + ni * 16 + l15;
    float bv = be[col];
#pragma unroll
    for (int mi = 0; mi < 4; mi++) {
#pragma unroll
      for (int r = 0; r < 4; r++) {
        int row = row_base + mi * 16 + quad * 4 + r;
        float v = acc[mi][ni][r] * inv_scale + bv;
        if (RELU) v = fmaxf(v, 0.f);
        size_t idx = (size_t)e * M * Ncols + (size_t)row * Ncols + col;
        if (OUT_MODE == 1) {
          float s = fminf(fmaxf(v * out_mult, -440.f), 440.f);
          unsigned int b8 = (unsigned int)__builtin_amdgcn_cvt_pk_fp8_f32(s, s, 0, 0) & 0xFF;
          ((unsigned char*)Cout)[idx] = (unsigned char)b8;
        } else if (OUT_MODE == 2) {
          ((unsigned short*)Cout)[idx] = f2bf(v);
        } else {
          ((float*)Cout)[idx] = v;
        }
      }
    }
  }
}

// ------- combine: out[n] = sum_s cw[n,s] * y[flat[n,s]], y in bf16 ----------
__global__ __launch_bounds__(256) void combine_kernel(
    const unsigned short* __restrict__ y, const int* __restrict__ flat_idx,
    const float* __restrict__ cw, float* __restrict__ out) {
  int n = blockIdx.x;
  float w0 = cw[n * 2], w1 = cw[n * 2 + 1];
  int f0 = flat_idx[n * 2], f1 = flat_idx[n * 2 + 1];
  const ushort2* y0 = (const ushort2*)(y + (size_t)f0 * DMODEL);
  const ushort2* y1 = (const ushort2*)(y + (size_t)f1 * DMODEL);
  float2* o = (float2*)(out + (size_t)n * DMODEL);
  int t = threadIdx.x;  // 256 threads x 2 elems x 2 iters = 1024
#pragma unroll
  for (int i = 0; i < 2; i++) {
    int j = t + i * 256;
    ushort2 a = y0[j], b = y1[j];
    float2 r;
    r.x = w0 * bf2f(a.x) + w1 * bf2f(b.x);
    r.y = w0 * bf2f(a.y) + w1 * bf2f(b.y);
    o[j] = r;
  }
}

extern "C" void kernel_launch(void* const* d_in, const int* in_sizes, int n_in,
                              void* d_out, int out_size, void* d_ws,
                              size_t ws_size, hipStream_t stream) {
  (void)in_sizes; (void)n_in; (void)out_size; (void)ws_size;
  const float* x     = (const float*)d_in[0];
  const float* wg    = (const float*)d_in[1];
  const float* fc1_w = (const float*)d_in[2];
  const float* fc1_b = (const float*)d_in[3];
  const float* fc2_w = (const float*)d_in[4];
  const float* fc2_b = (const float*)d_in[5];
  float* out = (float*)d_out;

  char* ws = (char*)d_ws;
  size_t o = 0;
  unsigned char* fc1t = (unsigned char*)(ws + o); o += (size_t)NEXP * DMODEL * HDIM;  // 32MB
  unsigned char* fc2t = (unsigned char*)(ws + o); o += (size_t)NEXP * DMODEL * HDIM;  // 32MB
  unsigned char* disp = (unsigned char*)(ws + o); o += (size_t)NEXP * CAP * DMODEL;   // 16MB
  unsigned char* hbuf = (unsigned char*)(ws + o); o += (size_t)NEXP * CAP * HDIM;     // 64MB
  unsigned short* ybuf = (unsigned short*)(ws + o); o += (size_t)NEXP * CAP * DMODEL * 2;  // 32MB bf16
  float* topv = (float*)(ws + o); o += (size_t)N_TOK * 2 * 4;
  int* topi   = (int*)(ws + o);   o += (size_t)N_TOK * 2 * 4;
  int* flat   = (int*)(ws + o);   o += (size_t)N_TOK * 2 * 4;
  float* cw   = (float*)(ws + o); o += (size_t)N_TOK * 2 * 4;
  float* mep  = (float*)(ws + o); o += (size_t)GATE_BLOCKS * NEXP * 4;
  int* cep    = (int*)(ws + o);   o += (size_t)GATE_BLOCKS * NEXP * 4;

  // no memset of disp: unwritten capacity rows are never gathered (cw==0),
  // and fp8-e4m3 bit patterns are always finite.

  // fused: both weight transposes (independent) + gate (dep-chain head)
  gate_transpose_kernel<<<dim3(64, 48), 256, 0, stream>>>(
      fc1_w, fc1t, fc2_w, fc2t, x, wg, topv, topi, mep, cep);
  // scan also computes l_aux (fused)
  scan_kernel<<<1, 1024, 0, stream>>>(topi, topv, flat, cw, mep, cep,
                                      out + (size_t)N_TOK * DMODEL);
  dispatch_kernel<<<N_TOK * 2, 64, 0, stream>>>(x, flat, cw, disp);
  // h = relu(disp@fc1^T /512 + b1); stored as fp8 of h*16
  gemm_fp8_kernel<DMODEL, true, 1>
      <<<dim3(HDIM / 128, CAP / 128, NEXP), 256, 0, stream>>>(
          disp, fc1t, fc1_b, hbuf, CAP, HDIM, 1.f / 512.f, 16.f);
  // y = (h*16)@(fc2*512)^T /8192 + b2 ; bf16
  gemm_fp8_kernel<HDIM, false, 2>
      <<<dim3(DMODEL / 128, CAP / 128, NEXP), 256, 0, stream>>>(
          hbuf, fc2t, fc2_b, ybuf, CAP, DMODEL, 1.f / 8192.f, 1.f);
  combine_kernel<<<N_TOK, 256, 0, stream>>>(ybuf, flat, cw, out);
}